// Round 6
// baseline (838.777 us; speedup 1.0000x reference)
//
#include <hip/hip_runtime.h>
#include <hip/hip_bf16.h>

typedef __attribute__((ext_vector_type(8))) short short8;
typedef __attribute__((ext_vector_type(4))) float f32x4;

#define B_ROWS 65536

__device__ inline unsigned short f2bf(float v) {
    __hip_bfloat16 h = __float2bfloat16(v);
    unsigned short u;
    __builtin_memcpy(&u, &h, 2);
    return u;
}

__device__ inline float bf2f(unsigned short u) {
    union { unsigned int i; float f; } cv;
    cv.i = ((unsigned int)u) << 16;
    return cv.f;
}

// ---------------- x fp32 [B,937] -> bf16 [B,960], block-per-row coalesced ----------------
__global__ __launch_bounds__(256) void convert_x_kernel(const float* __restrict__ x,
                                                        __hip_bfloat16* __restrict__ xb) {
    __shared__ __attribute__((aligned(16))) unsigned short ls[960];
    const int r = blockIdx.x;
    const int t = threadIdx.x;
    const float* xr = x + (size_t)r * 937;
#pragma unroll
    for (int p = 0; p < 4; ++p) {
        int c = t + p * 256;
        if (c < 937) ls[c] = f2bf(xr[c]);
        else if (c < 960) ls[c] = 0;
    }
    __syncthreads();
    if (t < 120)
        *(short8*)(xb + (size_t)r * 960 + t * 8) = *(const short8*)&ls[t * 8];
}

// ---------------- weight prep: w [K,N] fp32 -> wT [Npad,Kpad] bf16 ----------------
struct WDesc { const float* src; __hip_bfloat16* dst; int N, K, Npad, Kpad; };
struct WDescs { WDesc d[7]; };

__global__ void prep_weights_kernel(WDescs descs) {
    WDesc w = descs.d[blockIdx.y];
    int kg_count = w.Kpad >> 3;
    int per = w.Npad * kg_count;
    for (int i = blockIdx.x * blockDim.x + threadIdx.x; i < per; i += gridDim.x * blockDim.x) {
        int n = i % w.Npad;
        int kg = i / w.Npad;
        int k0 = kg << 3;
        short8 r;
#pragma unroll
        for (int j = 0; j < 8; ++j) {
            int k = k0 + j;
            float v = (n < w.N && k < w.K) ? w.src[(size_t)k * w.N + n] : 0.0f;
            r[j] = (short)f2bf(v);
        }
        *(short8*)((char*)w.dst + ((size_t)n * w.Kpad + (size_t)k0) * 2) = r;
    }
}

// ---------------- tail weight prep: Wh1 = [vw1|aw1], Wh2 = blockdiag(vw2,aw2); bias pack ----------------
struct TailArgs {
    const float *vw1, *vb1, *aw1, *ab1, *vw2, *vb2, *aw2, *ab2;
    const float *b4, *b5, *b6, *b7;
    __hip_bfloat16* Wtail;   // 6 x [256][256]; slots 4,5 filled here
    float* Bs;               // 6 x 256
};

__global__ void prep_tail_kernel(TailArgs a) {
    int g = blockIdx.x * 256 + threadIdx.x;    // [0, 131072)
    int half = g >> 16;                        // 0: Wh1, 1: Wh2
    int j = g & 65535;
    int n = j >> 8, k = j & 255;
    float v;
    if (half == 0) {
        v = (n < 128) ? a.vw1[(size_t)k * 128 + n] : a.aw1[(size_t)k * 128 + (n - 128)];
    } else {
        if (n < 64 && k < 128)                 v = a.vw2[(size_t)k * 64 + n];
        else if (n >= 64 && n < 128 && k >= 128) v = a.aw2[(size_t)(k - 128) * 64 + (n - 64)];
        else                                   v = 0.0f;
    }
    a.Wtail[(size_t)(4 + half) * 65536 + j] = __float2bfloat16(v);

    if (g < 1536) {
        int l = g >> 8, nn = g & 255;
        float bv;
        if (l == 0) bv = a.b4[nn];
        else if (l == 1) bv = a.b5[nn];
        else if (l == 2) bv = a.b6[nn];
        else if (l == 3) bv = a.b7[nn];
        else if (l == 4) bv = (nn < 128) ? a.vb1[nn] : a.ab1[nn - 128];
        else             bv = (nn < 64) ? a.vb2[nn] : (nn < 128 ? a.ab2[nn - 64] : 0.0f);
        a.Bs[g] = bv;
    }
}

// ---------------- MFMA GEMM (m97 structure) for L1..L3 ----------------
#define BM 128
#define BN 128
#define BK 64

__global__ __launch_bounds__(256) void gemm_bias_relu(
    const __hip_bfloat16* __restrict__ A,
    const __hip_bfloat16* __restrict__ Bt,
    const float* __restrict__ bias,
    __hip_bfloat16* __restrict__ C,
    int K, int N, int relu)
{
    __shared__ __attribute__((aligned(16))) __hip_bfloat16 sA[BM][BK];
    __shared__ __attribute__((aligned(16))) __hip_bfloat16 sB[BN][BK];

    const int t = threadIdx.x;
    const int wid = t >> 6;
    const int lane = t & 63;
    const int brow = blockIdx.x * BM;
    const int bcol = blockIdx.y * BN;
    const int wr = wid >> 1, wc = wid & 1;

    f32x4 acc[4][4] = {};

    const __hip_bfloat16* ga = A + (size_t)(brow + (t >> 3)) * K + (t & 7) * 8;
    const __hip_bfloat16* gb = Bt + (size_t)(bcol + (t >> 3)) * K + (t & 7) * 8;

    for (int k0 = 0; k0 < K; k0 += BK) {
#pragma unroll
        for (int it = 0; it < 4; ++it) {
            __builtin_amdgcn_global_load_lds(
                (const __attribute__((address_space(1))) void*)(ga + (size_t)it * 32 * K + k0),
                (__attribute__((address_space(3))) void*)((char*)&sA[0][0] + it * 4096 + wid * 1024),
                16, 0, 0);
            __builtin_amdgcn_global_load_lds(
                (const __attribute__((address_space(1))) void*)(gb + (size_t)it * 32 * K + k0),
                (__attribute__((address_space(3))) void*)((char*)&sB[0][0] + it * 4096 + wid * 1024),
                16, 0, 0);
        }
        __syncthreads();
#pragma unroll
        for (int kk = 0; kk < 2; ++kk) {
            short8 af[4], bfr[4];
#pragma unroll
            for (int m = 0; m < 4; ++m)
                af[m] = *(const short8*)&sA[wr * 64 + m * 16 + (lane & 15)][kk * 32 + (lane >> 4) * 8];
#pragma unroll
            for (int n = 0; n < 4; ++n)
                bfr[n] = *(const short8*)&sB[wc * 64 + n * 16 + (lane & 15)][kk * 32 + (lane >> 4) * 8];
#pragma unroll
            for (int m = 0; m < 4; ++m)
#pragma unroll
                for (int n = 0; n < 4; ++n)
                    acc[m][n] = __builtin_amdgcn_mfma_f32_16x16x32_bf16(af[m], bfr[n], acc[m][n], 0, 0, 0);
        }
        __syncthreads();
    }

    float biasv[4];
#pragma unroll
    for (int n = 0; n < 4; ++n) {
        int col = bcol + wc * 64 + n * 16 + (lane & 15);
        biasv[n] = (col < N) ? bias[col] : 0.0f;
    }
#pragma unroll
    for (int m = 0; m < 4; ++m) {
        int row = brow + wr * 64 + m * 16 + ((lane >> 4) << 2);
#pragma unroll
        for (int n = 0; n < 4; ++n) {
            int col = bcol + wc * 64 + n * 16 + (lane & 15);
            if (col < N) {
#pragma unroll
                for (int r = 0; r < 4; ++r) {
                    float v = acc[m][n][r] + biasv[n];
                    if (relu) v = fmaxf(v, 0.0f);
                    C[(size_t)(row + r) * N + col] = __float2bfloat16(v);
                }
            }
        }
    }
}

// ---------------- fused tail: h3 -> L4..L7 -> heads -> masking -> out ----------------
// 512 threads = 8 waves in a 2(M) x 4(N) grid; each wave owns a 64x64 output tile
// -> acc[4][4] (64 VGPRs) instead of acc[8][4] (128, which spilled in R4: FETCH
// showed +100 MB scratch traffic). Activation [128][256] bf16 in LDS, XOR-swizzled
// (byte ^= (row&7)<<4) against the stride-512B ds_read_b128 conflict.

__device__ __forceinline__ char* swzp(char* base, int row, int byte_in_row) {
    return base + row * 512 + (byte_in_row ^ ((row & 7) << 4));
}

__global__ __launch_bounds__(512, 4) void fused_tail(
    const __hip_bfloat16* __restrict__ h3,
    const __hip_bfloat16* __restrict__ Wtail,
    const float* __restrict__ Bs,
    const float* __restrict__ vw3, const float* __restrict__ vb3,
    const float* __restrict__ aw3, const float* __restrict__ ab3,
    const int* __restrict__ suicides, const int* __restrict__ invalid,
    float* __restrict__ out)
{
    __shared__ __attribute__((aligned(16))) unsigned char sAct[128 * 512];
    __shared__ float svw[64];
    __shared__ float saw[256];

    const int t = threadIdx.x;
    const int wid = t >> 6;
    const int lane = t & 63;
    const int brow = blockIdx.x * 128;
    const int wr = wid >> 2;          // 0..1 : 64-row band
    const int wc = wid & 3;           // 0..3 : 64-col band
    const int mrbase = wr * 64;
    const int wnbase = wc * 64;

    if (t < 64) svw[t] = vw3[t];
    if (t < 256) saw[t] = aw3[t];

    // stage h3 tile -> sAct (swizzled). thread t: row t>>2, col quarter (t&3)*64.
    {
        const __hip_bfloat16* src = h3 + (size_t)brow * 256;
        int r = t >> 2, c0 = (t & 3) * 64;
#pragma unroll
        for (int j = 0; j < 8; ++j) {
            short8 v = *(const short8*)(src + (size_t)r * 256 + c0 + j * 8);
            *(short8*)swzp((char*)sAct, r, (c0 + j * 8) * 2) = v;
        }
    }
    __syncthreads();

    for (int layer = 0; layer < 6; ++layer) {
        const __hip_bfloat16* W = Wtail + (size_t)layer * 65536;
        const float* bias = Bs + layer * 256;

        f32x4 acc[4][4] = {};
#pragma unroll
        for (int kk = 0; kk < 8; ++kk) {
            short8 bfrag[4];
#pragma unroll
            for (int n = 0; n < 4; ++n)
                bfrag[n] = *(const short8*)(W + (size_t)(wnbase + n * 16 + (lane & 15)) * 256
                                            + kk * 32 + (lane >> 4) * 8);
            short8 afrag[4];
#pragma unroll
            for (int m = 0; m < 4; ++m) {
                int r = mrbase + m * 16 + (lane & 15);
                afrag[m] = *(const short8*)swzp((char*)sAct, r, (kk * 32 + (lane >> 4) * 8) * 2);
            }
#pragma unroll
            for (int m = 0; m < 4; ++m)
#pragma unroll
                for (int n = 0; n < 4; ++n)
                    acc[m][n] = __builtin_amdgcn_mfma_f32_16x16x32_bf16(afrag[m], bfrag[n], acc[m][n], 0, 0, 0);
        }
        __syncthreads();   // all reads of sAct complete

        float bv[4];
#pragma unroll
        for (int n = 0; n < 4; ++n) bv[n] = bias[wnbase + n * 16 + (lane & 15)];
#pragma unroll
        for (int m = 0; m < 4; ++m) {
#pragma unroll
            for (int n = 0; n < 4; ++n) {
                int col = wnbase + n * 16 + (lane & 15);
#pragma unroll
                for (int r4 = 0; r4 < 4; ++r4) {
                    int row = mrbase + m * 16 + ((lane >> 4) << 2) + r4;
                    float v = fmaxf(acc[m][n][r4] + bv[n], 0.0f);
                    *(unsigned short*)swzp((char*)sAct, row, col * 2) = f2bf(v);
                }
            }
        }
        __syncthreads();
    }

    // final: v2 at cols 0..63, a2 at cols 64..127. 4 threads per row, 16 k's each.
    {
        int row = t >> 2;            // 0..127
        int part = t & 3;            // k-chunk
        int k0 = part * 16;

        float vsum = 0.0f;
        float a0 = 0.0f, a1 = 0.0f, a2v = 0.0f, a3v = 0.0f;
#pragma unroll
        for (int h = 0; h < 2; ++h) {
            short8 hv8 = *(const short8*)swzp((char*)sAct, row, (k0 + h * 8) * 2);
            short8 ha8 = *(const short8*)swzp((char*)sAct, row, (64 + k0 + h * 8) * 2);
#pragma unroll
            for (int j = 0; j < 8; ++j) {
                int k = k0 + h * 8 + j;
                float hv = bf2f((unsigned short)hv8[j]);
                float ha = bf2f((unsigned short)ha8[j]);
                vsum += hv * svw[k];
                a0 += ha * saw[k * 4 + 0];
                a1 += ha * saw[k * 4 + 1];
                a2v += ha * saw[k * 4 + 2];
                a3v += ha * saw[k * 4 + 3];
            }
        }
        // reduce across the 4 threads of this row (lanes 4r..4r+3 within the wave)
        vsum += __shfl_xor(vsum, 1); vsum += __shfl_xor(vsum, 2);
        a0 += __shfl_xor(a0, 1);   a0 += __shfl_xor(a0, 2);
        a1 += __shfl_xor(a1, 1);   a1 += __shfl_xor(a1, 2);
        a2v += __shfl_xor(a2v, 1); a2v += __shfl_xor(a2v, 2);
        a3v += __shfl_xor(a3v, 1); a3v += __shfl_xor(a3v, 2);

        if (part == 0) {
            int grow = brow + row;
            float value = vsum + vb3[0];
            float adv[4] = { a0 + ab3[0], a1 + ab3[1], a2v + ab3[2], a3v + ab3[3] };

            int4 sv = *(const int4*)(suicides + (size_t)grow * 4);
            int s0 = sv.x != 0, s1 = sv.y != 0, s2 = sv.z != 0, s3 = sv.w != 0;
            int all_s = s0 & s1 & s2 & s3;
            int inv = invalid[grow];

            int sarr[4] = { s0, s1, s2, s3 };
            bool mask[4];
#pragma unroll
            for (int jj = 0; jj < 4; ++jj)
                mask[jj] = all_s ? (jj == inv) : (sarr[jj] != 0);

            float denom = all_s ? 3.0f : (float)(4 - (s0 + s1 + s2 + s3));
            float sum = 0.0f;
#pragma unroll
            for (int jj = 0; jj < 4; ++jj) if (!mask[jj]) sum += adv[jj];
            float mean = sum / denom;

            float ninf = -1.0e30f;   // finite sentinel (ref has -inf; |e-a| must not be nan)
            float4 o;
            o.x = mask[0] ? ninf : value + adv[0] - mean;
            o.y = mask[1] ? ninf : value + adv[1] - mean;
            o.z = mask[2] ? ninf : value + adv[2] - mean;
            o.w = mask[3] ? ninf : value + adv[3] - mean;
            *(float4*)(out + (size_t)grow * 4) = o;
        }
    }
}

// ---------------- launch ----------------
extern "C" void kernel_launch(void* const* d_in, const int* in_sizes, int n_in,
                              void* d_out, int out_size, void* d_ws, size_t ws_size,
                              hipStream_t stream) {
    const float* x = (const float*)d_in[0];
    const int* suicides = (const int*)d_in[1];
    const int* invalid = (const int*)d_in[2];

    char* ws = (char*)d_ws;
    size_t off = 0;
    auto alloc = [&](size_t bytes) { char* p = ws + off; off += (bytes + 255) & ~(size_t)255; return p; };

    __hip_bfloat16* wT1 = (__hip_bfloat16*)alloc((size_t)512 * 960 * 2);
    __hip_bfloat16* wT2 = (__hip_bfloat16*)alloc((size_t)512 * 512 * 2);
    __hip_bfloat16* wT3 = (__hip_bfloat16*)alloc((size_t)256 * 512 * 2);
    __hip_bfloat16* Wtail = (__hip_bfloat16*)alloc((size_t)6 * 65536 * 2);   // wT4..7, Wh1, Wh2
    float* Bs = (float*)alloc((size_t)6 * 256 * 4);

    __hip_bfloat16* actA = (__hip_bfloat16*)alloc((size_t)B_ROWS * 960 * 2);
    __hip_bfloat16* actB = (__hip_bfloat16*)alloc((size_t)B_ROWS * 512 * 2);

    // 1) weight prep
    WDescs descs;
    descs.d[0] = { (const float*)d_in[3],  wT1,              512, 937, 512, 960 };
    descs.d[1] = { (const float*)d_in[5],  wT2,              512, 512, 512, 512 };
    descs.d[2] = { (const float*)d_in[7],  wT3,              256, 512, 256, 512 };
    descs.d[3] = { (const float*)d_in[9],  Wtail + 0 * 65536, 256, 256, 256, 256 };
    descs.d[4] = { (const float*)d_in[11], Wtail + 1 * 65536, 256, 256, 256, 256 };
    descs.d[5] = { (const float*)d_in[13], Wtail + 2 * 65536, 256, 256, 256, 256 };
    descs.d[6] = { (const float*)d_in[15], Wtail + 3 * 65536, 256, 256, 256, 256 };
    prep_weights_kernel<<<dim3(240, 7), 256, 0, stream>>>(descs);

    TailArgs ta;
    ta.vw1 = (const float*)d_in[17]; ta.vb1 = (const float*)d_in[18];
    ta.vw2 = (const float*)d_in[19]; ta.vb2 = (const float*)d_in[20];
    ta.aw1 = (const float*)d_in[23]; ta.ab1 = (const float*)d_in[24];
    ta.aw2 = (const float*)d_in[25]; ta.ab2 = (const float*)d_in[26];
    ta.b4 = (const float*)d_in[10]; ta.b5 = (const float*)d_in[12];
    ta.b6 = (const float*)d_in[14]; ta.b7 = (const float*)d_in[16];
    ta.Wtail = Wtail; ta.Bs = Bs;
    prep_tail_kernel<<<512, 256, 0, stream>>>(ta);

    // 2) x -> bf16 padded
    convert_x_kernel<<<B_ROWS, 256, 0, stream>>>(x, actA);

    auto gemm = [&](const __hip_bfloat16* A, const __hip_bfloat16* Bt, const float* bias,
                    __hip_bfloat16* C, int K, int N, int Npad, int relu) {
        dim3 grid(B_ROWS / BM, Npad / BN);
        gemm_bias_relu<<<grid, 256, 0, stream>>>(A, Bt, bias, C, K, N, relu);
    };

    // 3) trunk L1..L3
    gemm(actA, wT1, (const float*)d_in[4], actB, 960, 512, 512, 1);   // h1
    gemm(actB, wT2, (const float*)d_in[6], actA, 512, 512, 512, 1);   // h2
    gemm(actA, wT3, (const float*)d_in[8], actB, 512, 256, 256, 1);   // h3 (in actB)

    // 4) fused L4..L7 + heads + masking
    fused_tail<<<B_ROWS / 128, 512, 0, stream>>>(
        actB, Wtail, Bs,
        (const float*)d_in[21], (const float*)d_in[22],
        (const float*)d_in[27], (const float*)d_in[28],
        suicides, invalid, (float*)d_out);

    (void)in_sizes; (void)n_in; (void)out_size; (void)ws_size;
}

// Round 8
// 793.743 us; speedup vs baseline: 1.0567x; 1.0567x over previous
//
#include <hip/hip_runtime.h>
#include <hip/hip_bf16.h>

typedef __attribute__((ext_vector_type(8))) short short8;
typedef __attribute__((ext_vector_type(4))) float f32x4;

#define B_ROWS 65536

__device__ inline unsigned short f2bf(float v) {
    __hip_bfloat16 h = __float2bfloat16(v);
    unsigned short u;
    __builtin_memcpy(&u, &h, 2);
    return u;
}

__device__ inline float bf2f(unsigned short u) {
    union { unsigned int i; float f; } cv;
    cv.i = ((unsigned int)u) << 16;
    return cv.f;
}

// ---------------- x fp32 [B,937] -> bf16 [B,960], block-per-row coalesced ----------------
__global__ __launch_bounds__(256) void convert_x_kernel(const float* __restrict__ x,
                                                        __hip_bfloat16* __restrict__ xb) {
    __shared__ __attribute__((aligned(16))) unsigned short ls[960];
    const int r = blockIdx.x;
    const int t = threadIdx.x;
    const float* xr = x + (size_t)r * 937;
#pragma unroll
    for (int p = 0; p < 4; ++p) {
        int c = t + p * 256;
        if (c < 937) ls[c] = f2bf(xr[c]);
        else if (c < 960) ls[c] = 0;
    }
    __syncthreads();
    if (t < 120)
        *(short8*)(xb + (size_t)r * 960 + t * 8) = *(const short8*)&ls[t * 8];
}

// ---------------- weight prep: w [K,N] fp32 -> wT [Npad,Kpad] bf16 ----------------
struct WDesc { const float* src; __hip_bfloat16* dst; int N, K, Npad, Kpad; };
struct WDescs { WDesc d[7]; };

__global__ void prep_weights_kernel(WDescs descs) {
    WDesc w = descs.d[blockIdx.y];
    int kg_count = w.Kpad >> 3;
    int per = w.Npad * kg_count;
    for (int i = blockIdx.x * blockDim.x + threadIdx.x; i < per; i += gridDim.x * blockDim.x) {
        int n = i % w.Npad;
        int kg = i / w.Npad;
        int k0 = kg << 3;
        short8 r;
#pragma unroll
        for (int j = 0; j < 8; ++j) {
            int k = k0 + j;
            float v = (n < w.N && k < w.K) ? w.src[(size_t)k * w.N + n] : 0.0f;
            r[j] = (short)f2bf(v);
        }
        *(short8*)((char*)w.dst + ((size_t)n * w.Kpad + (size_t)k0) * 2) = r;
    }
}

// ---------------- tail weight prep: Wh1 = [vw1|aw1], Wh2 = blockdiag(vw2,aw2); bias pack ----------------
struct TailArgs {
    const float *vw1, *vb1, *aw1, *ab1, *vw2, *vb2, *aw2, *ab2;
    const float *b4, *b5, *b6, *b7;
    __hip_bfloat16* Wtail;   // 6 x [256][256]; slots 4,5 filled here
    float* Bs;               // 6 x 256
};

__global__ void prep_tail_kernel(TailArgs a) {
    int g = blockIdx.x * 256 + threadIdx.x;    // [0, 131072)
    int half = g >> 16;                        // 0: Wh1, 1: Wh2
    int j = g & 65535;
    int n = j >> 8, k = j & 255;
    float v;
    if (half == 0) {
        v = (n < 128) ? a.vw1[(size_t)k * 128 + n] : a.aw1[(size_t)k * 128 + (n - 128)];
    } else {
        if (n < 64 && k < 128)                 v = a.vw2[(size_t)k * 64 + n];
        else if (n >= 64 && n < 128 && k >= 128) v = a.aw2[(size_t)(k - 128) * 64 + (n - 64)];
        else                                   v = 0.0f;
    }
    a.Wtail[(size_t)(4 + half) * 65536 + j] = __float2bfloat16(v);

    if (g < 1536) {
        int l = g >> 8, nn = g & 255;
        float bv;
        if (l == 0) bv = a.b4[nn];
        else if (l == 1) bv = a.b5[nn];
        else if (l == 2) bv = a.b6[nn];
        else if (l == 3) bv = a.b7[nn];
        else if (l == 4) bv = (nn < 128) ? a.vb1[nn] : a.ab1[nn - 128];
        else             bv = (nn < 64) ? a.vb2[nn] : (nn < 128 ? a.ab2[nn - 64] : 0.0f);
        a.Bs[g] = bv;
    }
}

// ---------------- MFMA GEMM (m97 structure) for L1..L3 ----------------
#define BM 128
#define BN 128
#define BK 64

__global__ __launch_bounds__(256) void gemm_bias_relu(
    const __hip_bfloat16* __restrict__ A,
    const __hip_bfloat16* __restrict__ Bt,
    const float* __restrict__ bias,
    __hip_bfloat16* __restrict__ C,
    int K, int N, int relu)
{
    __shared__ __attribute__((aligned(16))) __hip_bfloat16 sA[BM][BK];
    __shared__ __attribute__((aligned(16))) __hip_bfloat16 sB[BN][BK];

    const int t = threadIdx.x;
    const int wid = t >> 6;
    const int lane = t & 63;
    const int brow = blockIdx.x * BM;
    const int bcol = blockIdx.y * BN;
    const int wr = wid >> 1, wc = wid & 1;

    f32x4 acc[4][4] = {};

    const __hip_bfloat16* ga = A + (size_t)(brow + (t >> 3)) * K + (t & 7) * 8;
    const __hip_bfloat16* gb = Bt + (size_t)(bcol + (t >> 3)) * K + (t & 7) * 8;

    for (int k0 = 0; k0 < K; k0 += BK) {
#pragma unroll
        for (int it = 0; it < 4; ++it) {
            __builtin_amdgcn_global_load_lds(
                (const __attribute__((address_space(1))) void*)(ga + (size_t)it * 32 * K + k0),
                (__attribute__((address_space(3))) void*)((char*)&sA[0][0] + it * 4096 + wid * 1024),
                16, 0, 0);
            __builtin_amdgcn_global_load_lds(
                (const __attribute__((address_space(1))) void*)(gb + (size_t)it * 32 * K + k0),
                (__attribute__((address_space(3))) void*)((char*)&sB[0][0] + it * 4096 + wid * 1024),
                16, 0, 0);
        }
        __syncthreads();
#pragma unroll
        for (int kk = 0; kk < 2; ++kk) {
            short8 af[4], bfr[4];
#pragma unroll
            for (int m = 0; m < 4; ++m)
                af[m] = *(const short8*)&sA[wr * 64 + m * 16 + (lane & 15)][kk * 32 + (lane >> 4) * 8];
#pragma unroll
            for (int n = 0; n < 4; ++n)
                bfr[n] = *(const short8*)&sB[wc * 64 + n * 16 + (lane & 15)][kk * 32 + (lane >> 4) * 8];
#pragma unroll
            for (int m = 0; m < 4; ++m)
#pragma unroll
                for (int n = 0; n < 4; ++n)
                    acc[m][n] = __builtin_amdgcn_mfma_f32_16x16x32_bf16(af[m], bfr[n], acc[m][n], 0, 0, 0);
        }
        __syncthreads();
    }

    float biasv[4];
#pragma unroll
    for (int n = 0; n < 4; ++n) {
        int col = bcol + wc * 64 + n * 16 + (lane & 15);
        biasv[n] = (col < N) ? bias[col] : 0.0f;
    }
#pragma unroll
    for (int m = 0; m < 4; ++m) {
        int row = brow + wr * 64 + m * 16 + ((lane >> 4) << 2);
#pragma unroll
        for (int n = 0; n < 4; ++n) {
            int col = bcol + wc * 64 + n * 16 + (lane & 15);
            if (col < N) {
#pragma unroll
                for (int r = 0; r < 4; ++r) {
                    float v = acc[m][n][r] + biasv[n];
                    if (relu) v = fmaxf(v, 0.0f);
                    C[(size_t)(row + r) * N + col] = __float2bfloat16(v);
                }
            }
        }
    }
}

// ---------------- fused tail: h3 -> L4..L7 -> heads -> masking -> out ----------------
// 256 threads = 4 waves, block covers 64 rows (sAct 32 KB). Wave w owns the 64x64
// output tile at cols w*64 -> acc[4][4] = 64 AGPRs. __launch_bounds__(256,3) gives a
// 170-reg UNIFIED (VGPR+AGPR, gfx950) budget vs ~120 needed -> no spill (R4/R6's
// 135/197 MB excess FETCH + 40/62 MB WRITE was scratch: (512,4) capped the unified
// file at 128 and acc alone ate 64 of it). 3 blocks/CU by LDS (3x33 KB).
// sAct XOR-swizzled (byte ^= (row&7)<<4) against stride-512B ds_read_b128 conflicts.

__device__ __forceinline__ char* swzp(char* base, int row, int byte_in_row) {
    return base + row * 512 + (byte_in_row ^ ((row & 7) << 4));
}

__global__ __launch_bounds__(256, 3) void fused_tail(
    const __hip_bfloat16* __restrict__ h3,
    const __hip_bfloat16* __restrict__ Wtail,
    const float* __restrict__ Bs,
    const float* __restrict__ vw3, const float* __restrict__ vb3,
    const float* __restrict__ aw3, const float* __restrict__ ab3,
    const int* __restrict__ suicides, const int* __restrict__ invalid,
    float* __restrict__ out)
{
    __shared__ __attribute__((aligned(16))) unsigned char sAct[64 * 512];
    __shared__ float svw[64];
    __shared__ float saw[256];

    const int t = threadIdx.x;
    const int wid = t >> 6;
    const int lane = t & 63;
    const int brow = blockIdx.x * 64;
    const int wnbase = wid * 64;        // wave's 64-col band

    if (t < 64) svw[t] = vw3[t];
    saw[t] = aw3[t];

    // stage h3 tile -> sAct (swizzled). thread t: row t>>2 (0..63), col quarter (t&3)*64.
    {
        const __hip_bfloat16* src = h3 + (size_t)brow * 256;
        int r = t >> 2, c0 = (t & 3) * 64;
#pragma unroll
        for (int j = 0; j < 8; ++j) {
            short8 v = *(const short8*)(src + (size_t)r * 256 + c0 + j * 8);
            *(short8*)swzp((char*)sAct, r, (c0 + j * 8) * 2) = v;
        }
    }
    __syncthreads();

    for (int layer = 0; layer < 6; ++layer) {
        const __hip_bfloat16* W = Wtail + (size_t)layer * 65536;
        const float* bias = Bs + layer * 256;

        f32x4 acc[4][4] = {};
#pragma unroll
        for (int kk = 0; kk < 8; ++kk) {
            // low liveness: 4 bfrags live, then one afrag at a time
            short8 bfrag[4];
#pragma unroll
            for (int n = 0; n < 4; ++n)
                bfrag[n] = *(const short8*)(W + (size_t)(wnbase + n * 16 + (lane & 15)) * 256
                                            + kk * 32 + (lane >> 4) * 8);
#pragma unroll
            for (int m = 0; m < 4; ++m) {
                short8 af = *(const short8*)swzp((char*)sAct, m * 16 + (lane & 15),
                                                 (kk * 32 + (lane >> 4) * 8) * 2);
#pragma unroll
                for (int n = 0; n < 4; ++n)
                    acc[m][n] = __builtin_amdgcn_mfma_f32_16x16x32_bf16(af, bfrag[n], acc[m][n], 0, 0, 0);
            }
        }
        __syncthreads();   // all reads of sAct complete

        float bv[4];
#pragma unroll
        for (int n = 0; n < 4; ++n) bv[n] = bias[wnbase + n * 16 + (lane & 15)];
#pragma unroll
        for (int m = 0; m < 4; ++m) {
#pragma unroll
            for (int n = 0; n < 4; ++n) {
                int col = wnbase + n * 16 + (lane & 15);
#pragma unroll
                for (int r4 = 0; r4 < 4; ++r4) {
                    int row = m * 16 + ((lane >> 4) << 2) + r4;
                    float v = fmaxf(acc[m][n][r4] + bv[n], 0.0f);
                    *(unsigned short*)swzp((char*)sAct, row, col * 2) = f2bf(v);
                }
            }
        }
        __syncthreads();
    }

    // final: v2 at cols 0..63, a2 at cols 64..127. 4 threads per row, 16 k's each.
    {
        int row = t >> 2;            // 0..63
        int part = t & 3;            // k-chunk
        int k0 = part * 16;

        float vsum = 0.0f;
        float a0 = 0.0f, a1 = 0.0f, a2v = 0.0f, a3v = 0.0f;
#pragma unroll
        for (int h = 0; h < 2; ++h) {
            short8 hv8 = *(const short8*)swzp((char*)sAct, row, (k0 + h * 8) * 2);
            short8 ha8 = *(const short8*)swzp((char*)sAct, row, (64 + k0 + h * 8) * 2);
#pragma unroll
            for (int j = 0; j < 8; ++j) {
                int k = k0 + h * 8 + j;
                float hv = bf2f((unsigned short)hv8[j]);
                float ha = bf2f((unsigned short)ha8[j]);
                vsum += hv * svw[k];
                a0 += ha * saw[k * 4 + 0];
                a1 += ha * saw[k * 4 + 1];
                a2v += ha * saw[k * 4 + 2];
                a3v += ha * saw[k * 4 + 3];
            }
        }
        // reduce across the 4 threads of this row (consecutive lanes of one wave)
        vsum += __shfl_xor(vsum, 1); vsum += __shfl_xor(vsum, 2);
        a0 += __shfl_xor(a0, 1);   a0 += __shfl_xor(a0, 2);
        a1 += __shfl_xor(a1, 1);   a1 += __shfl_xor(a1, 2);
        a2v += __shfl_xor(a2v, 1); a2v += __shfl_xor(a2v, 2);
        a3v += __shfl_xor(a3v, 1); a3v += __shfl_xor(a3v, 2);

        if (part == 0) {
            int grow = brow + row;
            float value = vsum + vb3[0];
            float adv[4] = { a0 + ab3[0], a1 + ab3[1], a2v + ab3[2], a3v + ab3[3] };

            int4 sv = *(const int4*)(suicides + (size_t)grow * 4);
            int s0 = sv.x != 0, s1 = sv.y != 0, s2 = sv.z != 0, s3 = sv.w != 0;
            int all_s = s0 & s1 & s2 & s3;
            int inv = invalid[grow];

            int sarr[4] = { s0, s1, s2, s3 };
            bool mask[4];
#pragma unroll
            for (int jj = 0; jj < 4; ++jj)
                mask[jj] = all_s ? (jj == inv) : (sarr[jj] != 0);

            float denom = all_s ? 3.0f : (float)(4 - (s0 + s1 + s2 + s3));
            float sum = 0.0f;
#pragma unroll
            for (int jj = 0; jj < 4; ++jj) if (!mask[jj]) sum += adv[jj];
            float mean = sum / denom;

            float ninf = -1.0e30f;   // finite sentinel (ref has -inf; |e-a| must not be nan)
            float4 o;
            o.x = mask[0] ? ninf : value + adv[0] - mean;
            o.y = mask[1] ? ninf : value + adv[1] - mean;
            o.z = mask[2] ? ninf : value + adv[2] - mean;
            o.w = mask[3] ? ninf : value + adv[3] - mean;
            *(float4*)(out + (size_t)grow * 4) = o;
        }
    }
}

// ---------------- launch ----------------
extern "C" void kernel_launch(void* const* d_in, const int* in_sizes, int n_in,
                              void* d_out, int out_size, void* d_ws, size_t ws_size,
                              hipStream_t stream) {
    const float* x = (const float*)d_in[0];
    const int* suicides = (const int*)d_in[1];
    const int* invalid = (const int*)d_in[2];

    char* ws = (char*)d_ws;
    size_t off = 0;
    auto alloc = [&](size_t bytes) { char* p = ws + off; off += (bytes + 255) & ~(size_t)255; return p; };

    __hip_bfloat16* wT1 = (__hip_bfloat16*)alloc((size_t)512 * 960 * 2);
    __hip_bfloat16* wT2 = (__hip_bfloat16*)alloc((size_t)512 * 512 * 2);
    __hip_bfloat16* wT3 = (__hip_bfloat16*)alloc((size_t)256 * 512 * 2);
    __hip_bfloat16* Wtail = (__hip_bfloat16*)alloc((size_t)6 * 65536 * 2);   // wT4..7, Wh1, Wh2
    float* Bs = (float*)alloc((size_t)6 * 256 * 4);

    __hip_bfloat16* actA = (__hip_bfloat16*)alloc((size_t)B_ROWS * 960 * 2);
    __hip_bfloat16* actB = (__hip_bfloat16*)alloc((size_t)B_ROWS * 512 * 2);

    // 1) weight prep
    WDescs descs;
    descs.d[0] = { (const float*)d_in[3],  wT1,              512, 937, 512, 960 };
    descs.d[1] = { (const float*)d_in[5],  wT2,              512, 512, 512, 512 };
    descs.d[2] = { (const float*)d_in[7],  wT3,              256, 512, 256, 512 };
    descs.d[3] = { (const float*)d_in[9],  Wtail + 0 * 65536, 256, 256, 256, 256 };
    descs.d[4] = { (const float*)d_in[11], Wtail + 1 * 65536, 256, 256, 256, 256 };
    descs.d[5] = { (const float*)d_in[13], Wtail + 2 * 65536, 256, 256, 256, 256 };
    descs.d[6] = { (const float*)d_in[15], Wtail + 3 * 65536, 256, 256, 256, 256 };
    prep_weights_kernel<<<dim3(240, 7), 256, 0, stream>>>(descs);

    TailArgs ta;
    ta.vw1 = (const float*)d_in[17]; ta.vb1 = (const float*)d_in[18];
    ta.vw2 = (const float*)d_in[19]; ta.vb2 = (const float*)d_in[20];
    ta.aw1 = (const float*)d_in[23]; ta.ab1 = (const float*)d_in[24];
    ta.aw2 = (const float*)d_in[25]; ta.ab2 = (const float*)d_in[26];
    ta.b4 = (const float*)d_in[10]; ta.b5 = (const float*)d_in[12];
    ta.b6 = (const float*)d_in[14]; ta.b7 = (const float*)d_in[16];
    ta.Wtail = Wtail; ta.Bs = Bs;
    prep_tail_kernel<<<512, 256, 0, stream>>>(ta);

    // 2) x -> bf16 padded
    convert_x_kernel<<<B_ROWS, 256, 0, stream>>>(x, actA);

    auto gemm = [&](const __hip_bfloat16* A, const __hip_bfloat16* Bt, const float* bias,
                    __hip_bfloat16* C, int K, int N, int Npad, int relu) {
        dim3 grid(B_ROWS / BM, Npad / BN);
        gemm_bias_relu<<<grid, 256, 0, stream>>>(A, Bt, bias, C, K, N, relu);
    };

    // 3) trunk L1..L3
    gemm(actA, wT1, (const float*)d_in[4], actB, 960, 512, 512, 1);   // h1
    gemm(actB, wT2, (const float*)d_in[6], actA, 512, 512, 512, 1);   // h2
    gemm(actA, wT3, (const float*)d_in[8], actB, 512, 256, 256, 1);   // h3 (in actB)

    // 4) fused L4..L7 + heads + masking
    fused_tail<<<B_ROWS / 64, 256, 0, stream>>>(
        actB, Wtail, Bs,
        (const float*)d_in[21], (const float*)d_in[22],
        (const float*)d_in[27], (const float*)d_in[28],
        suicides, invalid, (float*)d_out);

    (void)in_sizes; (void)n_in; (void)out_size; (void)ws_size;
}